// Round 1
// baseline (297.307 us; speedup 1.0000x reference)
//
#include <hip/hip_runtime.h>
#include <hip/hip_bf16.h>
#include <math.h>

// Problem constants
#define INDIM 768
#define NROWS 32768       // 8*4096
#define KSEL  38          // selected bins (with duplicates)
#define NCOLS 76          // 2*KSEL
#define CPAD  96          // 76 padded to multiple of 32 (MFMA K)
#define HID   256
#define NPADJ 80          // 76 padded to multiple of 16 (layer2 N)
#define LN_EPS 1e-5f

typedef float  f32x4  __attribute__((ext_vector_type(4)));
typedef __bf16 bf16x8 __attribute__((ext_vector_type(8)));

#define MFMA16(a,b,c) __builtin_amdgcn_mfma_f32_16x16x32_bf16((a),(b),(c),0,0,0)

// ---------------- workspace layout (bytes) ----------------
// Bft  [96][768] bf16 : DFT basis, col-major-for-B-frag (rows 76..95 zero)
// Bst  [768][96] bf16 : synthesis basis * (2/768)        (cols 76..95 zero)
// W1b  [2][256][96] bf16 : layer1 weights (cols 76..95 zero)
// W2t  [2][80][256] bf16 : layer2 weights (rows 76..79 zero)
// xin  [32768][96] bf16 : DFT output
// Aw   [32768][96] bf16 : z coefficients
#define OFF_BFT 0
#define OFF_BST 147456
#define OFF_W1B 294912
#define OFF_W2T 393216
#define OFF_XIN 475136
#define OFF_AW  6766592

// ---------------- prep: build bf16 basis + weights ----------------
__global__ void k_prep(const int* __restrict__ idxs,
                       const float* __restrict__ mu_w1, const float* __restrict__ sg_w1,
                       const float* __restrict__ mu_w2, const float* __restrict__ sg_w2,
                       __bf16* __restrict__ Bft, __bf16* __restrict__ Bst,
                       __bf16* __restrict__ W1b, __bf16* __restrict__ W2t)
{
    int tid = blockIdx.x * blockDim.x + threadIdx.x;
    int nth = gridDim.x * blockDim.x;
    const float TH = 6.28318530717958647692f / (float)INDIM;

    // Bft [c=96][n=768]: c<38: cos(2pi f_c n/768), 38<=c<76: -sin, else 0
    for (int i = tid; i < CPAD * INDIM; i += nth) {
        int c = i / INDIM, n = i % INDIM;
        float v = 0.f;
        if (c < NCOLS) {
            int cc = (c < KSEL) ? c : c - KSEL;
            int f = idxs[cc];
            int m = (f * n) % INDIM;
            float s, co; sincosf(TH * (float)m, &s, &co);
            v = (c < KSEL) ? co : -s;
        }
        Bft[i] = (__bf16)v;
    }
    // Bst [n=768][c=96]: same values scaled by 2/768 (irfft norm)
    for (int i = tid; i < INDIM * CPAD; i += nth) {
        int n = i / CPAD, c = i % CPAD;
        float v = 0.f;
        if (c < NCOLS) {
            int cc = (c < KSEL) ? c : c - KSEL;
            int f = idxs[cc];
            int m = (f * n) % INDIM;
            float s, co; sincosf(TH * (float)m, &s, &co);
            v = ((c < KSEL) ? co : -s) * (2.0f / (float)INDIM);
        }
        Bst[i] = (__bf16)v;
    }
    // W1b [2][256][96]
    for (int i = tid; i < 2 * HID * CPAD; i += nth) {
        int mlp = i / (HID * CPAD); int rem = i % (HID * CPAD);
        int r = rem / CPAD, k = rem % CPAD;
        const float* W = mlp ? sg_w1 : mu_w1;
        W1b[i] = (__bf16)((k < NCOLS) ? W[r * NCOLS + k] : 0.f);
    }
    // W2t [2][80][256]
    for (int i = tid; i < 2 * NPADJ * HID; i += nth) {
        int mlp = i / (NPADJ * HID); int rem = i % (NPADJ * HID);
        int j = rem / HID, h = rem % HID;
        const float* W = mlp ? sg_w2 : mu_w2;
        W2t[i] = (__bf16)((j < NCOLS) ? W[j * HID + h] : 0.f);
    }
}

// ---------------- K1: DFT  xin[32768][96] = x @ Bft^T ----------------
// block 256 (4 waves), 64 rows/block; K-chunks of 64; N = 96 (6 n-tiles)
__global__ __launch_bounds__(256) void k_dft(const float* __restrict__ x,
                                             const __bf16* __restrict__ Bft,
                                             __bf16* __restrict__ xin)
{
    __shared__ __bf16 Alds[64 * 72];   // 64 rows x 64 k, stride 72 (pad)
    __shared__ __bf16 Blds[96 * 72];   // 96 cols x 64 k
    int tid = threadIdx.x;
    int w = tid >> 6, lane = tid & 63, q = lane >> 4, l16 = lane & 15;
    int r0 = blockIdx.x * 64;

    f32x4 acc[6] = {};
    for (int kc = 0; kc < 12; ++kc) {
        int k0 = kc * 64;
        // stage A: each thread 16 floats (one row segment), cvt to bf16
        {
            int row = tid >> 2;
            int seg = (tid & 3) << 4;
            const float4* src = (const float4*)(x + (size_t)(r0 + row) * INDIM + k0 + seg);
            float4 f0 = src[0], f1 = src[1], f2 = src[2], f3 = src[3];
            union { __bf16 h[8]; uint4 u; } p0, p1;
            p0.h[0]=(__bf16)f0.x; p0.h[1]=(__bf16)f0.y; p0.h[2]=(__bf16)f0.z; p0.h[3]=(__bf16)f0.w;
            p0.h[4]=(__bf16)f1.x; p0.h[5]=(__bf16)f1.y; p0.h[6]=(__bf16)f1.z; p0.h[7]=(__bf16)f1.w;
            p1.h[0]=(__bf16)f2.x; p1.h[1]=(__bf16)f2.y; p1.h[2]=(__bf16)f2.z; p1.h[3]=(__bf16)f2.w;
            p1.h[4]=(__bf16)f3.x; p1.h[5]=(__bf16)f3.y; p1.h[6]=(__bf16)f3.z; p1.h[7]=(__bf16)f3.w;
            *(uint4*)&Alds[row * 72 + seg]     = p0.u;
            *(uint4*)&Alds[row * 72 + seg + 8] = p1.u;
        }
        // stage B: 96 rows x 64 bf16 = 768 uint4
        for (int i = tid; i < 768; i += 256) {
            int br = i >> 3, sg = (i & 7) << 3;
            *(uint4*)&Blds[br * 72 + sg] = *(const uint4*)&Bft[(size_t)br * INDIM + k0 + sg];
        }
        __syncthreads();
        #pragma unroll
        for (int ks = 0; ks < 2; ++ks) {
            bf16x8 a = *(const bf16x8*)&Alds[(w * 16 + l16) * 72 + ks * 32 + q * 8];
            #pragma unroll
            for (int nt = 0; nt < 6; ++nt) {
                bf16x8 b = *(const bf16x8*)&Blds[(nt * 16 + l16) * 72 + ks * 32 + q * 8];
                acc[nt] = MFMA16(a, b, acc[nt]);
            }
        }
        __syncthreads();
    }
    // epilogue: D-frag col = l16 (+16*nt), row = q*4+r
    #pragma unroll
    for (int nt = 0; nt < 6; ++nt)
        #pragma unroll
        for (int r = 0; r < 4; ++r) {
            int rowg = r0 + w * 16 + q * 4 + r;
            xin[(size_t)rowg * CPAD + nt * 16 + l16] = (__bf16)acc[nt][r];
        }
}

static __device__ inline float gelu_exact(float v) {
    return v * 0.5f * (1.f + erff(v * 0.70710678118654752440f));
}

// ---------------- K2: fused MLPs + z -> Aw ----------------
// block 256 (4 waves), 64 rows/block, 16 rows per wave
__global__ __launch_bounds__(256) void k_mlp(
    const __bf16* __restrict__ xin, const __bf16* __restrict__ W1b, const __bf16* __restrict__ W2t,
    const float* __restrict__ mu_b1, const float* __restrict__ mu_g,
    const float* __restrict__ mu_be, const float* __restrict__ mu_b2,
    const float* __restrict__ sg_b1, const float* __restrict__ sg_g,
    const float* __restrict__ sg_be, const float* __restrict__ sg_b2,
    const float* __restrict__ eps, __bf16* __restrict__ Aw)
{
    __shared__ __bf16 hlds[4 * 16 * 264];  // per-wave 16x256 activations (stride 264)
    __shared__ float  zlds[4 * 16 * 96];   // per-wave z rows
    int tid = threadIdx.x;
    int w = tid >> 6, lane = tid & 63, q = lane >> 4, l16 = lane & 15;
    int rbase = blockIdx.x * 64 + w * 16;

    __bf16* hw = &hlds[w * 16 * 264];
    float*  zw = &zlds[w * 16 * 96];

    // hoist layer1 A-frags (K = 96 -> 3 k-steps)
    bf16x8 a1[3];
    #pragma unroll
    for (int ks = 0; ks < 3; ++ks)
        a1[ks] = *(const bf16x8*)&xin[(size_t)(rbase + l16) * CPAD + ks * 32 + q * 8];

    f32x4 o2[2][5];
    for (int mlp = 0; mlp < 2; ++mlp) {
        const __bf16* W1 = W1b + (size_t)mlp * HID * CPAD;
        const __bf16* W2 = W2t + (size_t)mlp * NPADJ * HID;
        const float* b1 = mlp ? sg_b1 : mu_b1;
        const float* g  = mlp ? sg_g  : mu_g;
        const float* be = mlp ? sg_be : mu_be;

        // layer1: H[16 rows][256] via 16 n-tiles x 3 k-steps
        f32x4 acc1[16] = {};
        #pragma unroll
        for (int nt = 0; nt < 16; ++nt) {
            #pragma unroll
            for (int ks = 0; ks < 3; ++ks) {
                bf16x8 b = *(const bf16x8*)&W1[(size_t)(nt * 16 + l16) * CPAD + ks * 32 + q * 8];
                acc1[nt] = MFMA16(a1[ks], b, acc1[nt]);
            }
        }
        // bias + LN stats (per output row = q*4+r, reduce across the 16 lanes of q-group)
        float s[4] = {0,0,0,0}, ss[4] = {0,0,0,0};
        #pragma unroll
        for (int nt = 0; nt < 16; ++nt) {
            float bb = b1[nt * 16 + l16];
            #pragma unroll
            for (int r = 0; r < 4; ++r) {
                float v = acc1[nt][r] + bb;
                acc1[nt][r] = v;
                s[r] += v; ss[r] += v * v;
            }
        }
        #pragma unroll
        for (int off = 1; off < 16; off <<= 1) {
            #pragma unroll
            for (int r = 0; r < 4; ++r) {
                s[r]  += __shfl_xor(s[r], off);
                ss[r] += __shfl_xor(ss[r], off);
            }
        }
        float mean[4], rstd[4];
        #pragma unroll
        for (int r = 0; r < 4; ++r) {
            mean[r] = s[r] * (1.f / 256.f);
            float var = ss[r] * (1.f / 256.f) - mean[r] * mean[r];
            rstd[r] = rsqrtf(var + LN_EPS);
        }
        // LN + gelu -> hlds (bf16), fragment transpose via LDS
        #pragma unroll
        for (int nt = 0; nt < 16; ++nt) {
            int i = nt * 16 + l16;
            float gv = g[i], bev = be[i];
            #pragma unroll
            for (int r = 0; r < 4; ++r) {
                float hn = (acc1[nt][r] - mean[r]) * rstd[r] * gv + bev;
                hw[(q * 4 + r) * 264 + i] = (__bf16)gelu_exact(hn);
            }
        }
        // layer2: O[16 rows][80] via 5 n-tiles x 8 k-steps (A from LDS)
        bf16x8 a2[8];
        #pragma unroll
        for (int ks = 0; ks < 8; ++ks)
            a2[ks] = *(const bf16x8*)&hw[l16 * 264 + ks * 32 + q * 8];
        f32x4 o[5] = {};
        #pragma unroll
        for (int nt = 0; nt < 5; ++nt) {
            #pragma unroll
            for (int ks = 0; ks < 8; ++ks) {
                bf16x8 b = *(const bf16x8*)&W2[(size_t)(nt * 16 + l16) * HID + ks * 32 + q * 8];
                o[nt] = MFMA16(a2[ks], b, o[nt]);
            }
        }
        #pragma unroll
        for (int nt = 0; nt < 5; ++nt) o2[mlp][nt] = o[nt];
    }
    // z = (mu + b2mu) + eps * (sg + b2sg) -> zlds
    #pragma unroll
    for (int nt = 0; nt < 5; ++nt) {
        int j = nt * 16 + l16;
        if (j < NCOLS) {
            float b2m = mu_b2[j], b2s = sg_b2[j];
            #pragma unroll
            for (int r = 0; r < 4; ++r) {
                int row16 = q * 4 + r;
                float e = eps[(size_t)(rbase + row16) * NCOLS + j];
                zw[row16 * 96 + j] = (o2[0][nt][r] + b2m) + e * (o2[1][nt][r] + b2s);
            }
        }
    }
    // zero pad cols 76..95
    {
        int row16 = lane >> 2;
        int c0 = 76 + (lane & 3) * 5;
        #pragma unroll
        for (int t = 0; t < 5; ++t) zw[row16 * 96 + c0 + t] = 0.f;
    }
    // coalesced bf16 write of A
    {
        int row16 = lane >> 2, cseg = (lane & 3) * 24;
        #pragma unroll
        for (int v = 0; v < 3; ++v) {
            union { __bf16 h[8]; uint4 u; } p;
            #pragma unroll
            for (int t = 0; t < 8; ++t) p.h[t] = (__bf16)zw[row16 * 96 + cseg + v * 8 + t];
            *(uint4*)&Aw[(size_t)(rbase + row16) * CPAD + cseg + v * 8] = p.u;
        }
    }
}

// ---------------- K3: synthesis  out = Aw @ Bst^T ----------------
__global__ __launch_bounds__(256) void k_synth(const __bf16* __restrict__ Aw,
                                               const __bf16* __restrict__ Bst,
                                               float* __restrict__ out)
{
    int tid = threadIdx.x;
    int w = tid >> 6, lane = tid & 63, q = lane >> 4, l16 = lane & 15;
    int rbase = blockIdx.x * 64 + w * 16;
    bf16x8 a[3];
    #pragma unroll
    for (int ks = 0; ks < 3; ++ks)
        a[ks] = *(const bf16x8*)&Aw[(size_t)(rbase + l16) * CPAD + ks * 32 + q * 8];
    for (int nt = 0; nt < 48; ++nt) {
        f32x4 acc = {};
        #pragma unroll
        for (int ks = 0; ks < 3; ++ks) {
            bf16x8 b = *(const bf16x8*)&Bst[(size_t)(nt * 16 + l16) * CPAD + ks * 32 + q * 8];
            acc = MFMA16(a[ks], b, acc);
        }
        #pragma unroll
        for (int r = 0; r < 4; ++r)
            out[(size_t)(rbase + q * 4 + r) * INDIM + nt * 16 + l16] = acc[r];
    }
}

extern "C" void kernel_launch(void* const* d_in, const int* in_sizes, int n_in,
                              void* d_out, int out_size, void* d_ws, size_t ws_size,
                              hipStream_t stream)
{
    const float* x     = (const float*)d_in[0];
    const float* eps   = (const float*)d_in[1];
    const int*   idxs  = (const int*)  d_in[2];
    const float* mu_w1 = (const float*)d_in[3];
    const float* mu_b1 = (const float*)d_in[4];
    const float* mu_g  = (const float*)d_in[5];
    const float* mu_be = (const float*)d_in[6];
    const float* mu_w2 = (const float*)d_in[7];
    const float* mu_b2 = (const float*)d_in[8];
    const float* sg_w1 = (const float*)d_in[9];
    const float* sg_b1 = (const float*)d_in[10];
    const float* sg_g  = (const float*)d_in[11];
    const float* sg_be = (const float*)d_in[12];
    const float* sg_w2 = (const float*)d_in[13];
    const float* sg_b2 = (const float*)d_in[14];
    float* out = (float*)d_out;

    char* ws = (char*)d_ws;
    __bf16* Bft = (__bf16*)(ws + OFF_BFT);
    __bf16* Bst = (__bf16*)(ws + OFF_BST);
    __bf16* W1b = (__bf16*)(ws + OFF_W1B);
    __bf16* W2t = (__bf16*)(ws + OFF_W2T);
    __bf16* xin = (__bf16*)(ws + OFF_XIN);
    __bf16* Aw  = (__bf16*)(ws + OFF_AW);

    hipLaunchKernelGGL(k_prep, dim3(256), dim3(256), 0, stream,
                       idxs, mu_w1, sg_w1, mu_w2, sg_w2, Bft, Bst, W1b, W2t);
    hipLaunchKernelGGL(k_dft, dim3(NROWS / 64), dim3(256), 0, stream, x, Bft, xin);
    hipLaunchKernelGGL(k_mlp, dim3(NROWS / 64), dim3(256), 0, stream,
                       xin, W1b, W2t, mu_b1, mu_g, mu_be, mu_b2,
                       sg_b1, sg_g, sg_be, sg_b2, eps, Aw);
    hipLaunchKernelGGL(k_synth, dim3(NROWS / 64), dim3(256), 0, stream, Aw, Bst, out);
}